// Round 8
// baseline (780.849 us; speedup 1.0000x reference)
//
#include <hip/hip_runtime.h>
#include <cstdint>

typedef short short8 __attribute__((ext_vector_type(8)));
typedef float f32x16 __attribute__((ext_vector_type(16)));

// Problem constants
#define NB 4
#define NN 4096
#define ND 576
#define BIGI 0x7FFFFFFF
#define NSLOT 32

// ws layout: A_hi (bf16) [b][tile128][kc18][512 chunks of 16B] = 9437184 shorts,
// then A_lo same size; then (float units):
#define INVN_OFF 9437184
#define CANDV_OFF 9439488
// CANDV: [b][32 slots][4096 rows][3] floats = 1,572,864
#define CANDI_OFF 11012352
// CANDI same size; end = 12,585,216 floats = 50.34 MB
// Chunk swizzle (baked into layout): chunk g = r*4 + c', source chunk
// c = c' ^ ((r>>1)&3), i.e. source k-span = c*8..c*8+7 of row r.

#define MFMA __builtin_amdgcn_mfma_f32_32x32x16_bf16

__device__ __forceinline__ unsigned short f2bf(float f) {
    unsigned u = __float_as_uint(f);
    u += 0x7FFFu + ((u >> 16) & 1u);   // round-to-nearest-even
    return (unsigned short)(u >> 16);
}

__device__ __forceinline__ void gload_lds16(const void* g, void* l) {
    __builtin_amdgcn_global_load_lds(
        (const __attribute__((address_space(1))) void*)g,
        (__attribute__((address_space(3))) void*)l, 16, 0, 0);
}

// Exact jax top_k comparator: bigger value wins; tie -> smaller index wins.
__device__ __forceinline__ void insert_cmp(float v, int m,
    float& v0, int& i0, float& v1, int& i1, float& v2, int& i2) {
    bool beat2 = (v > v2) || (v == v2 && m < i2);
    if (beat2) {
        bool beat1 = (v > v1) || (v == v1 && m < i1);
        if (beat1) {
            v2 = v1; i2 = i1;
            bool beat0 = (v > v0) || (v == v0 && m < i0);
            if (beat0) { v1 = v0; i1 = i0; v0 = v; i0 = m; }
            else       { v1 = v;  i1 = m; }
        } else { v2 = v; i2 = m; }
    }
}

// Kernel 1: per-(b,c) windowed sums of x^2 -> inv norms for the 9 kernel offsets.
__global__ __launch_bounds__(64) void norm_kernel(const float* __restrict__ x,
                                                  float* __restrict__ ws) {
    const int bc = blockIdx.x;          // b*64 + c
    const int lane = threadIdx.x;       // = column w
    const float* xp = x + ((size_t)bc << 12);
    float colsum = 0.f, v0 = 0.f, v63 = 0.f;
    for (int h = 0; h < 64; ++h) {
        const float val = xp[(h << 6) + lane];
        const float sq = val * val;
        colsum += sq;
        if (h == 0)  v0 = sq;
        if (h == 63) v63 = sq;
    }
    float total = colsum, row0 = v0, row63 = v63;
    #pragma unroll
    for (int o = 32; o > 0; o >>= 1) {
        total += __shfl_xor(total, o);
        row0  += __shfl_xor(row0, o);
        row63 += __shfl_xor(row63, o);
    }
    const float col0  = __shfl(colsum, 0);
    const float col63 = __shfl(colsum, 63);
    const float c00 = __shfl(v0, 0),  c0e = __shfl(v0, 63);
    const float ce0 = __shfl(v63, 0), cee = __shfl(v63, 63);
    if (lane < 9) {
        const int dh = lane / 3 - 1, dw = lane % 3 - 1;
        float S = total;
        if (dh == 1)  S -= row0;
        if (dh == -1) S -= row63;
        if (dw == 1)  S -= col0;
        if (dw == -1) S -= col63;
        if (dh == 1  && dw == 1)  S += c00;
        if (dh == 1  && dw == -1) S += c0e;
        if (dh == -1 && dw == 1)  S += ce0;
        if (dh == -1 && dw == -1) S += cee;
        float nrm = fmaxf(sqrtf(S), 1e-12f);
        ws[INVN_OFF + bc * 9 + lane] = 1.0f / nrm;
    }
}

// Kernel 2: split-bf16 materialization with baked chunk swizzle.
// blockIdx = (b*32+nt)*18+kc. Region = 512 chunks of 16B (8 bf16).
__global__ __launch_bounds__(256) void mat_kernel(const float* __restrict__ x,
                                                  float* __restrict__ ws) {
    const int bi = blockIdx.x;             // 2304 blocks
    const int b = bi / 576;
    const int rem = bi - b * 576;
    const int nt = rem / 18;
    const int kc = rem - nt * 18;
    unsigned short* AH = (unsigned short*)ws;
    unsigned short* AL = AH + 9437184;
    const float* invn = ws + INVN_OFF + b * 576;
    const int tid = threadIdx.x;
    #pragma unroll
    for (int hf2 = 0; hf2 < 2; ++hf2) {
        const int g = tid + hf2 * 256;     // output chunk 0..511
        const int row = g >> 2, cp = g & 3;
        const int c = cp ^ ((row >> 1) & 3);    // source chunk (swizzle)
        const int k0 = c * 8;
        const int n = nt * 128 + row;
        const int h = n >> 6, wc = n & 63;
        union { unsigned short us[8]; float4 f4; } uh, ul;
        #pragma unroll
        for (int j = 0; j < 8; ++j) {
            const int d = kc * 32 + k0 + j;
            const int ch = d / 9;
            const int p = d - ch * 9;
            const int r = h + p / 3 - 1, s2 = wc + p % 3 - 1;
            float val = 0.f;
            if ((unsigned)r < 64u && (unsigned)s2 < 64u)
                val = x[((size_t)(b * 64 + ch) << 12) + (r << 6) + s2];
            val *= invn[d];
            const unsigned short hb = f2bf(val);
            const float hfv = __uint_as_float(((unsigned)hb) << 16);
            const unsigned short lb = f2bf(val - hfv);
            uh.us[j] = hb; ul.us[j] = lb;
        }
        ((float4*)AH)[(size_t)bi * 512 + g] = uh.f4;
        ((float4*)AL)[(size_t)bi * 512 + g] = ul.f4;
    }
}

__device__ __forceinline__ short8 ldfrag(const short* p) {
    union { short8 s8; float4 f4; } u;
    u.f4 = *(const float4*)p;
    return u.s8;
}

// Kernel 3: SYMMETRIC Gram R = A^T A (split-bf16 hh+hl+lh), fused top-3.
// Work-halving: R is symmetric; compute each unordered 128-region pair (I<=J)
// ONCE (528 pairs/batch, 2112 blocks total = 0.52x the ordered MFMA count,
// which was the invariant cost across R0-R7 at ~46 cy/MFMA/CU).
// Off-diagonal blocks fold BOTH directions: n-side (rows I over J's cols) ->
// candidate slot J, and m-side (rows J over I's rows, via an LDS transpose of
// acc) -> slot I.  Diagonal blocks fold n-side only (tile is bitwise-symmetric
// in hh and ulp-equal in hl/lh; m-side would double-insert).
// Candidates: [b][32 slots][4096 rows][3]; slot sigma of row r covers m in
// region sigma, written exactly once (diag: slot Rr; n-side: slots J>Rr;
// m-side: slots I<Rr).  attn merges all 32 slots.
// Block: 256 thr = 4 waves (wn=w>>1 picks n-half, wm=w&1 picks m-half),
// wave tile 64n x 64m, acc[2][2]=64 AGPR.  An (I-region, shared): LDS 2x16KB
// double buffer, issue-early, one __syncthreads/kc.  Am (J-region): direct
// global->VGPR.  __launch_bounds__(256,4) -> 4 waves/SIMD (R7 gate).
// C/D: m_part = (reg&3)+8*(reg>>2)+4*(lane>>5), n_part = lane&31  [HW-verified]
__global__ void __launch_bounds__(256, 4) gram_kernel(float* ws) {
    __shared__ short sm[16384];   // 32 KB: 2 x {AnH[4096] AnL[4096]} shorts
    const int bx0 = blockIdx.x;
    const int bx = (bx0 & 7) * 264 + (bx0 >> 3);   // XCD swizzle (2112 = 8*264)
    const int b = bx / 528;
    int p = bx - b * 528;
    int I = 0;
    while (p >= 32 - I) { p -= 32 - I; ++I; }      // unrank upper-tri pair
    const int J = I + p;
    const int tid = threadIdx.x;
    const int w = tid >> 6, lane = tid & 63;
    const int l31 = lane & 31, kh2 = lane >> 5;
    const int wn = w >> 1, wm = w & 1;

    const unsigned short* AH = (const unsigned short*)ws;
    const unsigned short* AL = AH + 9437184;

    const int nRegBase = (b * 32 + I) * 18;    // + kc (An = I-region, 128 rows)
    const int mRegBase = (b * 32 + J) * 18;    // + kc (Am = J-region, 128 rows)

    // An frag LDS offsets within one buffer (shorts): H at 0, L at +4096.
    // frag(row r, src chunk c) at r*32 + ((c ^ ((r>>1)&3))<<3), c = kh2 + 2h
    int boff[2][2];
    #pragma unroll
    for (int ni = 0; ni < 2; ++ni)
        #pragma unroll
        for (int h = 0; h < 2; ++h) {
            const int r = wn * 64 + ni * 32 + l31;      // 0..127
            const int c = kh2 + 2 * h;
            boff[ni][h] = r * 32 + ((c ^ ((r >> 1) & 3)) << 3);
        }
    // Am in-region lane offsets (global direct loads)
    int amoff[2][2];
    #pragma unroll
    for (int mi = 0; mi < 2; ++mi)
        #pragma unroll
        for (int h = 0; h < 2; ++h) {
            const int rm = wm * 64 + mi * 32 + l31;     // 0..127
            const int c = kh2 + 2 * h;
            amoff[mi][h] = rm * 32 + ((c ^ ((rm >> 1) & 3)) << 3);
        }

    // prologue: stage An[kc=0] into buffer 0 (16 KB: 4 instr/thread)
    {
        const unsigned short* gH = AH + ((size_t)nRegBase << 12) + tid * 8;
        const unsigned short* gL = AL + ((size_t)nRegBase << 12) + tid * 8;
        gload_lds16(gH,        sm + tid * 8);
        gload_lds16(gH + 2048, sm + 2048 + tid * 8);
        gload_lds16(gL,        sm + 4096 + tid * 8);
        gload_lds16(gL + 2048, sm + 6144 + tid * 8);
    }
    __syncthreads();

    f32x16 acc[2][2];   // [mi][ni] -> 64 AGPRs
    #pragma unroll
    for (int mi = 0; mi < 2; ++mi)
        #pragma unroll
        for (int ni = 0; ni < 2; ++ni)
            #pragma unroll
            for (int e = 0; e < 16; ++e) acc[mi][ni][e] = 0.f;

    for (int kc = 0; kc < 18; ++kc) {
        const int cur = kc & 1;
        // issue next An stage first (overlaps with this kc's compute)
        if (kc < 17) {
            const unsigned short* gH = AH + ((size_t)(nRegBase + kc + 1) << 12) + tid * 8;
            const unsigned short* gL = AL + ((size_t)(nRegBase + kc + 1) << 12) + tid * 8;
            short* dstb = sm + ((cur ^ 1) << 13);
            gload_lds16(gH,        dstb + tid * 8);
            gload_lds16(gH + 2048, dstb + 2048 + tid * 8);
            gload_lds16(gL,        dstb + 4096 + tid * 8);
            gload_lds16(gL + 2048, dstb + 6144 + tid * 8);
        }
        // Am fragments: direct global->VGPR (wave-private)
        short8 amh[2][2], aml[2][2];   // [mi][h]
        {
            const short* rH = (const short*)(AH + ((size_t)(mRegBase + kc) << 12));
            const short* rL = (const short*)(AL + ((size_t)(mRegBase + kc) << 12));
            #pragma unroll
            for (int mi = 0; mi < 2; ++mi)
                #pragma unroll
                for (int h = 0; h < 2; ++h) {
                    amh[mi][h] = ldfrag(rH + amoff[mi][h]);
                    aml[mi][h] = ldfrag(rL + amoff[mi][h]);
                }
        }
        // An from LDS buffer cur + MFMA (per-acc limb order hh,hl,lh)
        const short* sb = sm + (cur << 13);
        #pragma unroll
        for (int h = 0; h < 2; ++h) {
            #pragma unroll
            for (int ni = 0; ni < 2; ++ni) {
                const short8 bh = ldfrag(sb + boff[ni][h]);
                const short8 bl = ldfrag(sb + boff[ni][h] + 4096);
                #pragma unroll
                for (int mi = 0; mi < 2; ++mi) {
                    acc[mi][ni] = MFMA(amh[mi][h], bh, acc[mi][ni], 0, 0, 0);
                    acc[mi][ni] = MFMA(amh[mi][h], bl, acc[mi][ni], 0, 0, 0);
                    acc[mi][ni] = MFMA(aml[mi][h], bh, acc[mi][ni], 0, 0, 0);
                }
            }
        }
        __syncthreads();
    }

    // ---- n-side fold: rows of I (n = wn*64+ni*32+l31), m over J's 128 cols
    float t0v[2], t1v[2], t2v[2];
    int   t0i[2], t1i[2], t2i[2];
    #pragma unroll
    for (int i = 0; i < 2; ++i) {
        t0v[i] = t1v[i] = t2v[i] = -INFINITY;
        t0i[i] = t1i[i] = t2i[i] = BIGI;
    }
    #pragma unroll
    for (int ni = 0; ni < 2; ++ni)
        #pragma unroll
        for (int mi = 0; mi < 2; ++mi)
            #pragma unroll
            for (int v = 0; v < 16; ++v) {
                const int m = J * 128 + wm * 64 + mi * 32 + (v & 3) + 8 * (v >> 2) + 4 * kh2;
                insert_cmp(acc[mi][ni][v], m,
                           t0v[ni], t0i[ni], t1v[ni], t1i[ni], t2v[ni], t2i[ni]);
            }
    #pragma unroll
    for (int ni = 0; ni < 2; ++ni) {
        const float pv0 = __shfl_xor(t0v[ni], 32), pv1 = __shfl_xor(t1v[ni], 32),
                    pv2 = __shfl_xor(t2v[ni], 32);
        const int pi0 = __shfl_xor(t0i[ni], 32), pi1 = __shfl_xor(t1i[ni], 32),
                  pi2 = __shfl_xor(t2i[ni], 32);
        insert_cmp(pv0, pi0, t0v[ni], t0i[ni], t1v[ni], t1i[ni], t2v[ni], t2i[ni]);
        insert_cmp(pv1, pi1, t0v[ni], t0i[ni], t1v[ni], t1i[ni], t2v[ni], t2i[ni]);
        insert_cmp(pv2, pi2, t0v[ni], t0i[ni], t1v[ni], t1i[ni], t2v[ni], t2i[ni]);
    }

    // ---- m-side fold (off-diag only): rows of J (m), n over I's 128 rows.
    // Transpose acc via per-wave LDS scratch (staging area is dead now).
    float m0v[2], m1v[2], m2v[2];
    int   m0i[2], m1i[2], m2i[2];
    if (I != J) {
        float* scr = (float*)sm + w * 2048;   // 8KB per wave (32KB total)
        #pragma unroll
        for (int mi = 0; mi < 2; ++mi) {
            if (mi == 1) __syncthreads();     // scratch reuse between passes
            // write 32m x 64n subtile: scr[m32*64 + n_local]
            #pragma unroll
            for (int ni = 0; ni < 2; ++ni)
                #pragma unroll
                for (int v = 0; v < 16; ++v) {
                    const int m32 = (v & 3) + 8 * (v >> 2) + 4 * kh2;
                    scr[m32 * 64 + ni * 32 + l31] = acc[mi][ni][v];
                }
            // read row m32 = l31; kh2 splits the n-scan
            m0v[mi] = m1v[mi] = m2v[mi] = -INFINITY;
            m0i[mi] = m1i[mi] = m2i[mi] = BIGI;
            #pragma unroll
            for (int j = 0; j < 32; ++j) {
                const float val = scr[l31 * 64 + kh2 * 32 + j];
                const int n_g = I * 128 + wn * 64 + kh2 * 32 + j;
                insert_cmp(val, n_g, m0v[mi], m0i[mi], m1v[mi], m1i[mi], m2v[mi], m2i[mi]);
            }
        }
        #pragma unroll
        for (int mi = 0; mi < 2; ++mi) {
            const float pv0 = __shfl_xor(m0v[mi], 32), pv1 = __shfl_xor(m1v[mi], 32),
                        pv2 = __shfl_xor(m2v[mi], 32);
            const int pi0 = __shfl_xor(m0i[mi], 32), pi1 = __shfl_xor(m1i[mi], 32),
                      pi2 = __shfl_xor(m2i[mi], 32);
            insert_cmp(pv0, pi0, m0v[mi], m0i[mi], m1v[mi], m1i[mi], m2v[mi], m2i[mi]);
            insert_cmp(pv1, pi1, m0v[mi], m0i[mi], m1v[mi], m1i[mi], m2v[mi], m2i[mi]);
            insert_cmp(pv2, pi2, m0v[mi], m0i[mi], m1v[mi], m1i[mi], m2v[mi], m2i[mi]);
        }
    }

    // ---- cross-wave merges through LDS
    __syncthreads();
    float* cv  = (float*)sm;              // n-side: [w4][ni2][l32][3] = 768 f
    int*   ci  = (int*)sm + 768;
    float* mv  = (float*)sm + 1536;       // m-side: [w4][mi2][l32][3] = 768 f
    int*   miI = (int*)sm + 2304;
    if (kh2 == 0) {
        #pragma unroll
        for (int ni = 0; ni < 2; ++ni) {
            const int base = ((w * 2 + ni) * 32 + l31) * 3;
            cv[base] = t0v[ni]; cv[base + 1] = t1v[ni]; cv[base + 2] = t2v[ni];
            ci[base] = t0i[ni]; ci[base + 1] = t1i[ni]; ci[base + 2] = t2i[ni];
        }
        if (I != J) {
            #pragma unroll
            for (int mi = 0; mi < 2; ++mi) {
                const int base = ((w * 2 + mi) * 32 + l31) * 3;
                mv[base] = m0v[mi]; mv[base + 1] = m1v[mi]; mv[base + 2] = m2v[mi];
                miI[base] = m0i[mi]; miI[base + 1] = m1i[mi]; miI[base + 2] = m2i[mi];
            }
        }
    }
    __syncthreads();
    int* wsi = (int*)ws;
    if (tid < 128) {
        // n-side final: merge the two wm waves sharing (wn, ni, l)
        const int wn2 = tid >> 6, ni = (tid >> 5) & 1, l = tid & 31;
        float v0 = -INFINITY, v1 = -INFINITY, v2 = -INFINITY;
        int i0 = BIGI, i1 = BIGI, i2 = BIGI;
        #pragma unroll
        for (int wm2 = 0; wm2 < 2; ++wm2) {
            const int w2 = wn2 * 2 + wm2;
            const int base = ((w2 * 2 + ni) * 32 + l) * 3;
            #pragma unroll
            for (int j = 0; j < 3; ++j)
                insert_cmp(cv[base + j], ci[base + j], v0, i0, v1, i1, v2, i2);
        }
        const size_t o = ((size_t)(b * NSLOT + J) * NN + I * 128 + tid) * 3;
        ws[CANDV_OFF + o] = v0; ws[CANDV_OFF + o + 1] = v1; ws[CANDV_OFF + o + 2] = v2;
        wsi[CANDI_OFF + o] = i0; wsi[CANDI_OFF + o + 1] = i1; wsi[CANDI_OFF + o + 2] = i2;
    } else if (I != J) {
        // m-side final: merge the two wn waves sharing (wm, mi, l)
        const int tid2 = tid - 128;
        const int wm2 = tid2 >> 6, mi = (tid2 >> 5) & 1, l = tid2 & 31;
        float v0 = -INFINITY, v1 = -INFINITY, v2 = -INFINITY;
        int i0 = BIGI, i1 = BIGI, i2 = BIGI;
        #pragma unroll
        for (int wn2 = 0; wn2 < 2; ++wn2) {
            const int w2 = wn2 * 2 + wm2;
            const int base = ((w2 * 2 + mi) * 32 + l) * 3;
            #pragma unroll
            for (int j = 0; j < 3; ++j)
                insert_cmp(mv[base + j], miI[base + j], v0, i0, v1, i1, v2, i2);
        }
        const size_t o = ((size_t)(b * NSLOT + I) * NN + J * 128 + tid2) * 3;
        ws[CANDV_OFF + o] = v0; ws[CANDV_OFF + o + 1] = v1; ws[CANDV_OFF + o + 2] = v2;
        wsi[CANDI_OFF + o] = i0; wsi[CANDI_OFF + o + 1] = i1; wsi[CANDI_OFF + o + 2] = i2;
    }
}

// Kernel 4: merge 32 slot candidates -> global top-3; 27-way attention. One wave per n.
__global__ __launch_bounds__(256) void attn_kernel(const float* __restrict__ x,
                                                   const float* __restrict__ ws,
                                                   float* __restrict__ out) {
    const int wid = threadIdx.x >> 6;
    const int lane = threadIdx.x & 63;
    const int gw = blockIdx.x * 4 + wid;   // 0..16383
    const int b = gw >> 12;
    const int n = gw & 4095;

    float v0 = -INFINITY, v1 = -INFINITY, v2 = -INFINITY;
    int i0 = BIGI, i1 = BIGI, i2 = BIGI;
    const int* wi = (const int*)ws;
    for (int s = 0; s < NSLOT; ++s) {
        const size_t o = ((size_t)(b * NSLOT + s) * NN + n) * 3;
        #pragma unroll
        for (int j = 0; j < 3; ++j)
            insert_cmp(ws[CANDV_OFF + o + j], wi[CANDI_OFF + o + j], v0, i0, v1, i1, v2, i2);
    }
    const int idx3[3] = {i0, i1, i2};

    // per-lane feature meta for d = a*64 + lane  (torch reshape: K[...,a,c'] = xu[a*64+c'])
    int cc[9], dhh[9], dww[9];
    float inr[9];
    #pragma unroll
    for (int a = 0; a < 9; ++a) {
        const int d = a * 64 + lane;
        const int c = d / 9;
        const int p = d - c * 9;
        cc[a] = c; dhh[a] = p / 3 - 1; dww[a] = p - (p / 3) * 3 - 1;
        inr[a] = ws[INVN_OFF + b * ND + d];
    }
    const float q = x[((size_t)(b * 64 + lane) << 12) + n];

    float rv[27], sc[27];
    #pragma unroll
    for (int k = 0; k < 3; ++k) {
        const int m = idx3[k];
        const int hm = m >> 6, wm = m & 63;
        #pragma unroll
        for (int a = 0; a < 9; ++a) {
            const int r = hm + dhh[a], s2 = wm + dww[a];
            float val = 0.f;
            if ((unsigned)r < 64u && (unsigned)s2 < 64u)
                val = x[((size_t)(b * 64 + cc[a]) << 12) + (r << 6) + s2];
            const float rr = val * inr[a];
            rv[k * 9 + a] = rr;
            float t = q * rr;
            #pragma unroll
            for (int o2 = 32; o2 > 0; o2 >>= 1) t += __shfl_xor(t, o2);
            sc[k * 9 + a] = t * 0.125f;   // / sqrt(64)
        }
    }
    float mx = -INFINITY;
    #pragma unroll
    for (int u = 0; u < 27; ++u) mx = fmaxf(mx, sc[u]);
    float sum = 0.f;
    #pragma unroll
    for (int u = 0; u < 27; ++u) { const float e = expf(sc[u] - mx); sc[u] = e; sum += e; }
    const float inv = 1.0f / sum;
    float o = 0.f;
    #pragma unroll
    for (int u = 0; u < 27; ++u) o += sc[u] * rv[u];
    out[((size_t)gw << 6) + lane] = o * inv;
}

extern "C" void kernel_launch(void* const* d_in, const int* in_sizes, int n_in,
                              void* d_out, int out_size, void* d_ws, size_t ws_size,
                              hipStream_t stream) {
    (void)in_sizes; (void)n_in; (void)out_size; (void)ws_size;
    const float* x = (const float*)d_in[0];
    float* ws = (float*)d_ws;
    float* out = (float*)d_out;

    hipLaunchKernelGGL(norm_kernel, dim3(NB * 64), dim3(64), 0, stream, x, ws);
    hipLaunchKernelGGL(mat_kernel, dim3(2304), dim3(256), 0, stream, x, ws);
    hipLaunchKernelGGL(gram_kernel, dim3(2112), dim3(256), 0, stream, ws);
    hipLaunchKernelGGL(attn_kernel, dim3(4096), dim3(256), 0, stream, x, ws, out);
}